// Round 4
// baseline (275.031 us; speedup 1.0000x reference)
//
#include <hip/hip_runtime.h>

#define N_TOK 256
#define CP    128
#define CHD   32
#define NH    4
#define NT    65536   // N_TOK*N_TOK
#define NCOL  528     // 512 (q|k|v|g) + 4 (b) + 12 pad
#define PNS   136     // padded LDS stride (shorts)
#define PLS   264     // attn pl row stride (shorts)

typedef short short8 __attribute__((ext_vector_type(8)));
typedef short short4v __attribute__((ext_vector_type(4)));
typedef float f32x4  __attribute__((ext_vector_type(4)));
typedef float float4v __attribute__((ext_vector_type(4)));
typedef unsigned uint2v __attribute__((ext_vector_type(2)));

__device__ __forceinline__ short f2bf(float f) {
    unsigned u = __builtin_bit_cast(unsigned, f);
    u += 0x7fffu + ((u >> 16) & 1u);   // RTNE
    return (short)(u >> 16);
}
__device__ __forceinline__ float bf2f(short s) {
    unsigned u = ((unsigned)(unsigned short)s) << 16;
    return __builtin_bit_cast(float, u);
}
__device__ __forceinline__ unsigned pk_bf2(float a, float b) {
    unsigned lo = (unsigned)(unsigned short)f2bf(a);
    unsigned hi = (unsigned)(unsigned short)f2bf(b);
    return lo | (hi << 16);
}

// ---------------------------------------------------------------- kernel 0
__global__ void pack_weights(const float* __restrict__ Wq, const float* __restrict__ Wk,
                             const float* __restrict__ Wv, const float* __restrict__ Wb,
                             const float* __restrict__ Wg, const float* __restrict__ Wout,
                             short* __restrict__ wcat, short* __restrict__ woutT) {
    int idx = blockIdx.x * 256 + threadIdx.x;
    if (idx < NCOL * CP) {
        int n = idx >> 7, k = idx & 127;
        float v = 0.f;
        if (n < 512) {
            const float* W = (n < 128) ? Wq : (n < 256) ? Wk : (n < 384) ? Wv : Wg;
            v = W[k * 128 + (n & 127)];
        } else if (n < 516) {
            v = Wb[k * 4 + (n - 512)];
        }
        wcat[n * CP + k] = f2bf(v);
    } else {
        int j = idx - NCOL * CP;
        if (j < 128 * 128) {
            int n = j >> 7, k = j & 127;
            woutT[n * 128 + k] = f2bf(Wout[k * 128 + n]);
        }
    }
}

// ---------------------------------------------------------------- kernel 1
// LN (fp32) + projections (bf16 MFMA).  q pre-scaled by 1/sqrt(32);
// v stored TRANSPOSED (vtT[c][token]) for attn's PV A-operand.
__global__ __launch_bounds__(256, 4)
void ln_proj(const float* __restrict__ pair, const float* __restrict__ gamma,
             const float* __restrict__ beta, const short* __restrict__ wcat,
             short* __restrict__ qt, short* __restrict__ kt,
             short* __restrict__ vtT, short* __restrict__ gt,
             float* __restrict__ bt) {
    __shared__ short pn[64 * PNS];
    __shared__ short sbuf[64 * PNS];
    const int tid = threadIdx.x;
    const int wv = tid >> 6, lane = tid & 63;
    const int quad = lane >> 4, l15 = lane & 15;
    const int r0 = blockIdx.x * 64;
    const int c = lane & 31, half = lane >> 5;

    float4v ga = *(const float4v*)&gamma[4 * c];
    float4v be = *(const float4v*)&beta[4 * c];

    #pragma unroll 4
    for (int p = 0; p < 8; ++p) {
        int row = wv * 16 + p * 2 + half;
        float4v x = *(const float4v*)(pair + (size_t)(r0 + row) * CP + 4 * c);
        float s  = (x[0] + x[1]) + (x[2] + x[3]);
        float q2 = (x[0] * x[0] + x[1] * x[1]) + (x[2] * x[2] + x[3] * x[3]);
        #pragma unroll
        for (int m = 1; m < 32; m <<= 1) {
            s  += __shfl_xor(s, m, 32);
            q2 += __shfl_xor(q2, m, 32);
        }
        float mu = s * (1.f / 128.f);
        float var = q2 * (1.f / 128.f) - mu * mu;
        float rs = rsqrtf(var + 1e-5f);
        unsigned y0 = (unsigned)(unsigned short)f2bf((x[0] - mu) * rs * ga[0] + be[0]);
        unsigned y1 = (unsigned)(unsigned short)f2bf((x[1] - mu) * rs * ga[1] + be[1]);
        unsigned y2 = (unsigned)(unsigned short)f2bf((x[2] - mu) * rs * ga[2] + be[2]);
        unsigned y3 = (unsigned)(unsigned short)f2bf((x[3] - mu) * rs * ga[3] + be[3]);
        uint2v pk = {y0 | (y1 << 16), y2 | (y3 << 16)};
        *(uint2v*)&pn[row * PNS + 4 * c] = pk;
    }

    short8 afrag[4];
    #pragma unroll
    for (int s = 0; s < 4; ++s)
        afrag[s] = *(const short8*)&pn[(wv * 16 + l15) * PNS + s * 32 + quad * 8];

    for (int grp = 0; grp < 4; ++grp) {
        f32x4 acc[8];
        #pragma unroll
        for (int c8 = 0; c8 < 8; ++c8) {
            acc[c8] = f32x4{0.f, 0.f, 0.f, 0.f};
            #pragma unroll
            for (int s = 0; s < 4; ++s) {
                short8 bfrag = *(const short8*)&wcat[(size_t)(grp * 128 + c8 * 16 + l15) * CP + s * 32 + quad * 8];
                acc[c8] = __builtin_amdgcn_mfma_f32_16x16x32_bf16(afrag[s], bfrag, acc[c8], 0, 0, 0);
            }
        }
        if (grp == 0) {           // fold 1/sqrt(32) into q
            #pragma unroll
            for (int c8 = 0; c8 < 8; ++c8)
                #pragma unroll
                for (int r = 0; r < 4; ++r)
                    acc[c8][r] *= 0.17677669529663687f;
        }
        if (grp == 3) {
            #pragma unroll
            for (int c8 = 0; c8 < 8; ++c8)
                #pragma unroll
                for (int r = 0; r < 4; ++r)
                    acc[c8][r] = 1.f / (1.f + __expf(-acc[c8][r]));   // sigmoid gate
        }
        #pragma unroll
        for (int c8 = 0; c8 < 8; ++c8)
            #pragma unroll
            for (int r = 0; r < 4; ++r)
                sbuf[(wv * 16 + quad * 4 + r) * PNS + c8 * 16 + l15] = f2bf(acc[c8][r]);

        if (grp == 2) {
            // wave-private transpose: v -> vtT[c][token]
            int c0 = lane * 2;
            unsigned colw[16];
            #pragma unroll
            for (int rr = 0; rr < 16; ++rr)
                colw[rr] = *(const unsigned*)&sbuf[(wv * 16 + rr) * PNS + c0];
            #pragma unroll
            for (int p = 0; p < 8; ++p) {
                unsigned a = colw[2 * p], b = colw[2 * p + 1];
                unsigned w0 = (a & 0xFFFFu) | (b << 16);
                unsigned w1 = (a >> 16) | (b & 0xFFFF0000u);
                *(unsigned*)&vtT[(size_t)c0 * NT + r0 + wv * 16 + 2 * p] = w0;
                *(unsigned*)&vtT[(size_t)(c0 + 1) * NT + r0 + wv * 16 + 2 * p] = w1;
            }
        } else {
            int row = wv * 16 + (lane >> 2);
            short* dst = (grp == 0) ? qt : (grp == 1) ? kt : gt;
            #pragma unroll
            for (int rep = 0; rep < 4; ++rep) {   // rep = head
                short8 v8 = *(const short8*)&sbuf[row * PNS + rep * 32 + (lane & 3) * 8];
                *(short8*)(dst + ((size_t)rep * NT + r0 + row) * CHD + (lane & 3) * 8) = v8;
            }
        }
    }
    // bias chunk
    f32x4 accb = f32x4{0.f, 0.f, 0.f, 0.f};
    #pragma unroll
    for (int s = 0; s < 4; ++s) {
        short8 bfrag = *(const short8*)&wcat[(size_t)(512 + l15) * CP + s * 32 + quad * 8];
        accb = __builtin_amdgcn_mfma_f32_16x16x32_bf16(afrag[s], bfrag, accb, 0, 0, 0);
    }
    if (l15 < 4) {
        #pragma unroll
        for (int r = 0; r < 4; ++r)
            bt[l15 * NT + r0 + wv * 16 + quad * 4 + r] = accb[r];
    }
}

// ---------------------------------------------------------------- kernel 2
// Attention per (i,h), S^T orientation.  Lane holds col j=l15.
// QK^T: A=K, B=Q, C=bias (f32x4 direct load).  Softmax: in-lane tree +
// 2 shuffles.  P^T->LDS as ds_write_b64, PV: A=V^T (global), B=P^T (LDS).
// Zero barriers; LDS = 33 KB (pl only).
__global__ __launch_bounds__(256, 4)
void attn(const short* __restrict__ qt, const short* __restrict__ kt,
          const short* __restrict__ vtT, const short* __restrict__ gt,
          const float* __restrict__ bt, short* __restrict__ og) {
    __shared__ short pl[4 * 16 * PLS];
    const int tid = threadIdx.x;
    const int h = blockIdx.x >> 8, i = blockIdx.x & 255;
    const int wv = tid >> 6, lane = tid & 63;
    const int quad = lane >> 4, l15 = lane & 15;

    const short* kbase = kt + ((size_t)h * NT + (size_t)i * 256) * CHD;
    const short* qbase = qt + ((size_t)h * NT + (size_t)i * 256) * CHD;
    const short* gbase = gt + ((size_t)h * NT + (size_t)i * 256) * CHD;
    const short* vbase = vtT + (size_t)h * 32 * NT + (size_t)i * 256;
    const float* bbase = bt + (size_t)h * NT;
    short* plw = &pl[wv * 16 * PLS];

    for (int jt = 0; jt < 4; ++jt) {
        const int jbase = jt * 64 + wv * 16;
        const int j = jbase + l15;           // this lane's column
        // B-fragment: q row j (q pre-scaled by 1/sqrt(32))
        short8 qf = *(const short8*)(qbase + (size_t)j * CHD + quad * 8);

        // S^T tiles: D[k_local][j], C = bias b[j][k] (f32x4, r = k+0..3)
        f32x4 sacc[16];
        #pragma unroll
        for (int t = 0; t < 16; ++t) {
            short8 kf = *(const short8*)(kbase + (size_t)(t * 16 + l15) * CHD + quad * 8);
            f32x4 bv = *(const f32x4*)(bbase + (size_t)j * 256 + t * 16 + quad * 4);
            sacc[t] = __builtin_amdgcn_mfma_f32_16x16x32_bf16(kf, qf, bv, 0, 0, 0);
        }
        // softmax over k: in-lane tree, then cross-quad (2 shuffle levels)
        f32x4 vm = sacc[0];
        #pragma unroll
        for (int t = 1; t < 16; ++t) {
            vm[0] = fmaxf(vm[0], sacc[t][0]); vm[1] = fmaxf(vm[1], sacc[t][1]);
            vm[2] = fmaxf(vm[2], sacc[t][2]); vm[3] = fmaxf(vm[3], sacc[t][3]);
        }
        float m = fmaxf(fmaxf(vm[0], vm[1]), fmaxf(vm[2], vm[3]));
        m = fmaxf(m, __shfl_xor(m, 16));
        m = fmaxf(m, __shfl_xor(m, 32));
        f32x4 vs = {0.f, 0.f, 0.f, 0.f};
        #pragma unroll
        for (int t = 0; t < 16; ++t) {
            f32x4 e;
            e[0] = __expf(sacc[t][0] - m); e[1] = __expf(sacc[t][1] - m);
            e[2] = __expf(sacc[t][2] - m); e[3] = __expf(sacc[t][3] - m);
            sacc[t] = e;
            vs += e;
        }
        float s = (vs[0] + vs[1]) + (vs[2] + vs[3]);
        s += __shfl_xor(s, 16);
        s += __shfl_xor(s, 32);
        const float invs = 1.f / s;          // normalization deferred to O

        // P^T (unnormalized e, bf16) -> LDS: one b64 per tile, conflict-free
        #pragma unroll
        for (int t = 0; t < 16; ++t) {
            uint2v w = {pk_bf2(sacc[t][0], sacc[t][1]), pk_bf2(sacc[t][2], sacc[t][3])};
            *(uint2v*)&plw[l15 * PLS + t * 16 + quad * 4] = w;
        }
        // PV: O^T[c][j] = sum_k V^T[c][k] * P^T[k][j]
        f32x4 o0 = {0.f, 0.f, 0.f, 0.f}, o1 = {0.f, 0.f, 0.f, 0.f};
        #pragma unroll
        for (int ks = 0; ks < 8; ++ks) {
            short8 pf = *(const short8*)&plw[l15 * PLS + ks * 32 + quad * 8];
            short8 v0 = *(const short8*)(vbase + (size_t)l15 * NT + ks * 32 + quad * 8);
            short8 v1 = *(const short8*)(vbase + (size_t)(16 + l15) * NT + ks * 32 + quad * 8);
            o0 = __builtin_amdgcn_mfma_f32_16x16x32_bf16(v0, pf, o0, 0, 0, 0);
            o1 = __builtin_amdgcn_mfma_f32_16x16x32_bf16(v1, pf, o1, 0, 0, 0);
        }
        // epilogue: normalize, gate, store (lane owns column j)
        short4v g0 = *(const short4v*)(gbase + (size_t)j * CHD + quad * 4);
        short4v g1 = *(const short4v*)(gbase + (size_t)j * CHD + 16 + quad * 4);
        uint2v w0 = {pk_bf2(o0[0] * invs * bf2f(g0[0]), o0[1] * invs * bf2f(g0[1])),
                     pk_bf2(o0[2] * invs * bf2f(g0[2]), o0[3] * invs * bf2f(g0[3]))};
        uint2v w1 = {pk_bf2(o1[0] * invs * bf2f(g1[0]), o1[1] * invs * bf2f(g1[1])),
                     pk_bf2(o1[2] * invs * bf2f(g1[2]), o1[3] * invs * bf2f(g1[3]))};
        size_t ob = ((size_t)i * 256 + j) * CP + h * CHD;
        *(uint2v*)&og[ob + quad * 4] = w0;
        *(uint2v*)&og[ob + 16 + quad * 4] = w1;
    }
}

// ---------------------------------------------------------------- kernel 3
__global__ __launch_bounds__(256, 4)
void out_gemm(const short* __restrict__ og, const short* __restrict__ woutT,
              float* __restrict__ out) {
    __shared__ short al[64 * PNS];
    const int tid = threadIdx.x;
    const int wv = tid >> 6, lane = tid & 63;
    const int quad = lane >> 4, l15 = lane & 15;
    const int r0 = blockIdx.x * 64;

    for (int g = tid; g < 1024; g += 256) {
        int row = g >> 4, p = g & 15;
        *(short8*)&al[row * PNS + p * 8] = *(const short8*)(og + (size_t)(r0 + row) * CP + p * 8);
    }
    __syncthreads();

    short8 af[4];
    #pragma unroll
    for (int s = 0; s < 4; ++s)
        af[s] = *(const short8*)&al[(wv * 16 + l15) * PNS + s * 32 + quad * 8];

    f32x4 acc[8];
    #pragma unroll
    for (int ch = 0; ch < 8; ++ch) {
        acc[ch] = f32x4{0.f, 0.f, 0.f, 0.f};
        #pragma unroll
        for (int s = 0; s < 4; ++s) {
            short8 bfrag = *(const short8*)&woutT[(size_t)(ch * 16 + l15) * 128 + s * 32 + quad * 8];
            acc[ch] = __builtin_amdgcn_mfma_f32_16x16x32_bf16(af[s], bfrag, acc[ch], 0, 0, 0);
        }
    }
    #pragma unroll
    for (int ch = 0; ch < 8; ++ch)
        #pragma unroll
        for (int r = 0; r < 4; ++r)
            out[(size_t)(r0 + wv * 16 + quad * 4 + r) * CP + ch * 16 + l15] = acc[ch][r];
}

// ---------------------------------------------------------------- launch
extern "C" void kernel_launch(void* const* d_in, const int* in_sizes, int n_in,
                              void* d_out, int out_size, void* d_ws, size_t ws_size,
                              hipStream_t stream) {
    (void)in_sizes; (void)n_in; (void)out_size; (void)ws_size;
    const float* pair  = (const float*)d_in[0];
    const float* gamma = (const float*)d_in[1];
    const float* beta  = (const float*)d_in[2];
    const float* Wq    = (const float*)d_in[3];
    const float* Wk    = (const float*)d_in[4];
    const float* Wv    = (const float*)d_in[5];
    const float* Wb    = (const float*)d_in[6];
    const float* Wg    = (const float*)d_in[7];
    const float* Wout  = (const float*)d_in[8];
    float* out = (float*)d_out;

    char* ws = (char*)d_ws;
    const size_t SZ_QKVG = (size_t)NH * NT * CHD * 2;           // 16 MB each
    short* wcat  = (short*)(ws);
    short* woutT = (short*)(ws + 135168);
    short* qt    = (short*)(ws + 167936);
    short* kt    = (short*)(ws + 167936 + SZ_QKVG);
    short* vtT   = (short*)(ws + 167936 + 2 * SZ_QKVG);          // [128][NT]
    short* gt    = (short*)(ws + 167936 + 3 * SZ_QKVG);
    float* bt    = (float*)(ws + 167936 + 4 * SZ_QKVG);
    short* og    = (short*)(ws + 167936 + 4 * SZ_QKVG + (size_t)NH * NT * 4);

    hipLaunchKernelGGL(pack_weights, dim3(328), dim3(256), 0, stream,
                       Wq, Wk, Wv, Wb, Wg, Wout, wcat, woutT);
    hipLaunchKernelGGL(ln_proj, dim3(1024), dim3(256), 0, stream,
                       pair, gamma, beta, wcat, qt, kt, vtT, gt, bt);
    hipLaunchKernelGGL(attn, dim3(1024), dim3(256), 0, stream,
                       qt, kt, vtT, gt, bt, og);
    hipLaunchKernelGGL(out_gemm, dim3(1024), dim3(256), 0, stream,
                       og, woutT, out);
}

// Round 5
// 273.709 us; speedup vs baseline: 1.0048x; 1.0048x over previous
//
#include <hip/hip_runtime.h>

#define N_TOK 256
#define CP    128
#define CHD   32
#define NH    4
#define NT    65536   // N_TOK*N_TOK
#define NCOL  528     // 512 (q|k|v|g) + 4 (b) + 12 pad
#define PNS   136     // padded LDS stride (shorts)
#define PLS   264     // attn pl row stride (shorts)

typedef short short8 __attribute__((ext_vector_type(8)));
typedef short short4v __attribute__((ext_vector_type(4)));
typedef float f32x4  __attribute__((ext_vector_type(4)));
typedef float float4v __attribute__((ext_vector_type(4)));
typedef unsigned uint2v __attribute__((ext_vector_type(2)));

__device__ __forceinline__ short f2bf(float f) {
    unsigned u = __builtin_bit_cast(unsigned, f);
    u += 0x7fffu + ((u >> 16) & 1u);   // RTNE
    return (short)(u >> 16);
}
__device__ __forceinline__ float bf2f(short s) {
    unsigned u = ((unsigned)(unsigned short)s) << 16;
    return __builtin_bit_cast(float, u);
}
__device__ __forceinline__ unsigned pk_bf2(float a, float b) {
    unsigned lo = (unsigned)(unsigned short)f2bf(a);
    unsigned hi = (unsigned)(unsigned short)f2bf(b);
    return lo | (hi << 16);
}

// ---------------------------------------------------------------- kernel 0
__global__ void pack_weights(const float* __restrict__ Wq, const float* __restrict__ Wk,
                             const float* __restrict__ Wv, const float* __restrict__ Wb,
                             const float* __restrict__ Wg, const float* __restrict__ Wout,
                             short* __restrict__ wcat, short* __restrict__ woutT) {
    int idx = blockIdx.x * 256 + threadIdx.x;
    if (idx < NCOL * CP) {
        int n = idx >> 7, k = idx & 127;
        float v = 0.f;
        if (n < 512) {
            const float* W = (n < 128) ? Wq : (n < 256) ? Wk : (n < 384) ? Wv : Wg;
            v = W[k * 128 + (n & 127)];
        } else if (n < 516) {
            v = Wb[k * 4 + (n - 512)];
        }
        wcat[n * CP + k] = f2bf(v);
    } else {
        int j = idx - NCOL * CP;
        if (j < 128 * 128) {
            int n = j >> 7, k = j & 127;
            woutT[n * 128 + k] = f2bf(Wout[k * 128 + n]);
        }
    }
}

// ---------------------------------------------------------------- kernel 1
// LN (fp32) + projections (bf16 MFMA).  q pre-scaled by 1/sqrt(32);
// v stored TRANSPOSED (vtT[c][token]) for attn's PV A-operand.
__global__ __launch_bounds__(256, 4)
void ln_proj(const float* __restrict__ pair, const float* __restrict__ gamma,
             const float* __restrict__ beta, const short* __restrict__ wcat,
             short* __restrict__ qt, short* __restrict__ kt,
             short* __restrict__ vtT, short* __restrict__ gt,
             float* __restrict__ bt) {
    __shared__ short pn[64 * PNS];
    __shared__ short sbuf[64 * PNS];
    const int tid = threadIdx.x;
    const int wv = tid >> 6, lane = tid & 63;
    const int quad = lane >> 4, l15 = lane & 15;
    const int r0 = blockIdx.x * 64;
    const int c = lane & 31, half = lane >> 5;

    float4v ga = *(const float4v*)&gamma[4 * c];
    float4v be = *(const float4v*)&beta[4 * c];

    #pragma unroll 4
    for (int p = 0; p < 8; ++p) {
        int row = wv * 16 + p * 2 + half;
        float4v x = *(const float4v*)(pair + (size_t)(r0 + row) * CP + 4 * c);
        float s  = (x[0] + x[1]) + (x[2] + x[3]);
        float q2 = (x[0] * x[0] + x[1] * x[1]) + (x[2] * x[2] + x[3] * x[3]);
        #pragma unroll
        for (int m = 1; m < 32; m <<= 1) {
            s  += __shfl_xor(s, m, 32);
            q2 += __shfl_xor(q2, m, 32);
        }
        float mu = s * (1.f / 128.f);
        float var = q2 * (1.f / 128.f) - mu * mu;
        float rs = rsqrtf(var + 1e-5f);
        unsigned y0 = (unsigned)(unsigned short)f2bf((x[0] - mu) * rs * ga[0] + be[0]);
        unsigned y1 = (unsigned)(unsigned short)f2bf((x[1] - mu) * rs * ga[1] + be[1]);
        unsigned y2 = (unsigned)(unsigned short)f2bf((x[2] - mu) * rs * ga[2] + be[2]);
        unsigned y3 = (unsigned)(unsigned short)f2bf((x[3] - mu) * rs * ga[3] + be[3]);
        uint2v pk = {y0 | (y1 << 16), y2 | (y3 << 16)};
        *(uint2v*)&pn[row * PNS + 4 * c] = pk;
    }

    short8 afrag[4];
    #pragma unroll
    for (int s = 0; s < 4; ++s)
        afrag[s] = *(const short8*)&pn[(wv * 16 + l15) * PNS + s * 32 + quad * 8];

    for (int grp = 0; grp < 4; ++grp) {
        f32x4 acc[8];
        #pragma unroll
        for (int c8 = 0; c8 < 8; ++c8) {
            acc[c8] = f32x4{0.f, 0.f, 0.f, 0.f};
            #pragma unroll
            for (int s = 0; s < 4; ++s) {
                short8 bfrag = *(const short8*)&wcat[(size_t)(grp * 128 + c8 * 16 + l15) * CP + s * 32 + quad * 8];
                acc[c8] = __builtin_amdgcn_mfma_f32_16x16x32_bf16(afrag[s], bfrag, acc[c8], 0, 0, 0);
            }
        }
        if (grp == 0) {           // fold 1/sqrt(32) into q
            #pragma unroll
            for (int c8 = 0; c8 < 8; ++c8)
                #pragma unroll
                for (int r = 0; r < 4; ++r)
                    acc[c8][r] *= 0.17677669529663687f;
        }
        if (grp == 3) {
            #pragma unroll
            for (int c8 = 0; c8 < 8; ++c8)
                #pragma unroll
                for (int r = 0; r < 4; ++r)
                    acc[c8][r] = 1.f / (1.f + __expf(-acc[c8][r]));   // sigmoid gate
        }
        #pragma unroll
        for (int c8 = 0; c8 < 8; ++c8)
            #pragma unroll
            for (int r = 0; r < 4; ++r)
                sbuf[(wv * 16 + quad * 4 + r) * PNS + c8 * 16 + l15] = f2bf(acc[c8][r]);

        if (grp == 2) {
            // wave-private transpose: v -> vtT[c][token]
            int c0 = lane * 2;
            unsigned colw[16];
            #pragma unroll
            for (int rr = 0; rr < 16; ++rr)
                colw[rr] = *(const unsigned*)&sbuf[(wv * 16 + rr) * PNS + c0];
            #pragma unroll
            for (int p = 0; p < 8; ++p) {
                unsigned a = colw[2 * p], b = colw[2 * p + 1];
                unsigned w0 = (a & 0xFFFFu) | (b << 16);
                unsigned w1 = (a >> 16) | (b & 0xFFFF0000u);
                *(unsigned*)&vtT[(size_t)c0 * NT + r0 + wv * 16 + 2 * p] = w0;
                *(unsigned*)&vtT[(size_t)(c0 + 1) * NT + r0 + wv * 16 + 2 * p] = w1;
            }
        } else {
            int row = wv * 16 + (lane >> 2);
            short* dst = (grp == 0) ? qt : (grp == 1) ? kt : gt;
            #pragma unroll
            for (int rep = 0; rep < 4; ++rep) {   // rep = head
                short8 v8 = *(const short8*)&sbuf[row * PNS + rep * 32 + (lane & 3) * 8];
                *(short8*)(dst + ((size_t)rep * NT + r0 + row) * CHD + (lane & 3) * 8) = v8;
            }
        }
    }
    // bias chunk
    f32x4 accb = f32x4{0.f, 0.f, 0.f, 0.f};
    #pragma unroll
    for (int s = 0; s < 4; ++s) {
        short8 bfrag = *(const short8*)&wcat[(size_t)(512 + l15) * CP + s * 32 + quad * 8];
        accb = __builtin_amdgcn_mfma_f32_16x16x32_bf16(afrag[s], bfrag, accb, 0, 0, 0);
    }
    if (l15 < 4) {
        #pragma unroll
        for (int r = 0; r < 4; ++r)
            bt[l15 * NT + r0 + wv * 16 + quad * 4 + r] = accb[r];
    }
}

// ---------------------------------------------------------------- kernel 2
// Attention per (i,h), S^T orientation.  XCD-aware swizzle clusters
// same-h blocks on one XCD so the 256 KB bias slice stays L2-resident.
// og stored as per-head planes [h][i*256+j][c] -> full-line writes.
__global__ __launch_bounds__(256, 4)
void attn(const short* __restrict__ qt, const short* __restrict__ kt,
          const short* __restrict__ vtT, const short* __restrict__ gt,
          const float* __restrict__ bt, short* __restrict__ og) {
    __shared__ short pl[4 * 16 * PLS];
    const int tid = threadIdx.x;
    // XCD-aware: blocks on XCD x (blk%8==x) walk h slowly (32 blocks per h)
    const int blk = blockIdx.x;
    const int xcd = blk & 7, m = blk >> 3;
    const int h = m >> 5;
    const int i = ((m & 31) << 3) | xcd;
    const int wv = tid >> 6, lane = tid & 63;
    const int quad = lane >> 4, l15 = lane & 15;

    const short* kbase = kt + ((size_t)h * NT + (size_t)i * 256) * CHD;
    const short* qbase = qt + ((size_t)h * NT + (size_t)i * 256) * CHD;
    const short* gbase = gt + ((size_t)h * NT + (size_t)i * 256) * CHD;
    const short* vbase = vtT + (size_t)h * 32 * NT + (size_t)i * 256;
    const float* bbase = bt + (size_t)h * NT;
    short* plw = &pl[wv * 16 * PLS];

    for (int jt = 0; jt < 4; ++jt) {
        const int jbase = jt * 64 + wv * 16;
        const int j = jbase + l15;           // this lane's column
        // B-fragment: q row j (q pre-scaled by 1/sqrt(32))
        short8 qf = *(const short8*)(qbase + (size_t)j * CHD + quad * 8);

        // S^T tiles: D[k_local][j], C = bias b[j][k] (f32x4, r = k+0..3)
        f32x4 sacc[16];
        #pragma unroll
        for (int t = 0; t < 16; ++t) {
            short8 kf = *(const short8*)(kbase + (size_t)(t * 16 + l15) * CHD + quad * 8);
            f32x4 bv = *(const f32x4*)(bbase + (size_t)j * 256 + t * 16 + quad * 4);
            sacc[t] = __builtin_amdgcn_mfma_f32_16x16x32_bf16(kf, qf, bv, 0, 0, 0);
        }
        // softmax over k: in-lane tree, then cross-quad (2 shuffle levels)
        f32x4 vm = sacc[0];
        #pragma unroll
        for (int t = 1; t < 16; ++t) {
            vm[0] = fmaxf(vm[0], sacc[t][0]); vm[1] = fmaxf(vm[1], sacc[t][1]);
            vm[2] = fmaxf(vm[2], sacc[t][2]); vm[3] = fmaxf(vm[3], sacc[t][3]);
        }
        float mx = fmaxf(fmaxf(vm[0], vm[1]), fmaxf(vm[2], vm[3]));
        mx = fmaxf(mx, __shfl_xor(mx, 16));
        mx = fmaxf(mx, __shfl_xor(mx, 32));
        f32x4 vs = {0.f, 0.f, 0.f, 0.f};
        #pragma unroll
        for (int t = 0; t < 16; ++t) {
            f32x4 e;
            e[0] = __expf(sacc[t][0] - mx); e[1] = __expf(sacc[t][1] - mx);
            e[2] = __expf(sacc[t][2] - mx); e[3] = __expf(sacc[t][3] - mx);
            sacc[t] = e;
            vs += e;
        }
        float s = (vs[0] + vs[1]) + (vs[2] + vs[3]);
        s += __shfl_xor(s, 16);
        s += __shfl_xor(s, 32);
        const float invs = 1.f / s;          // normalization deferred to O

        // P^T (unnormalized e, bf16) -> LDS: one b64 per tile, conflict-free
        #pragma unroll
        for (int t = 0; t < 16; ++t) {
            uint2v w = {pk_bf2(sacc[t][0], sacc[t][1]), pk_bf2(sacc[t][2], sacc[t][3])};
            *(uint2v*)&plw[l15 * PLS + t * 16 + quad * 4] = w;
        }
        // PV: O^T[c][j] = sum_k V^T[c][k] * P^T[k][j]
        f32x4 o0 = {0.f, 0.f, 0.f, 0.f}, o1 = {0.f, 0.f, 0.f, 0.f};
        #pragma unroll
        for (int ks = 0; ks < 8; ++ks) {
            short8 pf = *(const short8*)&plw[l15 * PLS + ks * 32 + quad * 8];
            short8 v0 = *(const short8*)(vbase + (size_t)l15 * NT + ks * 32 + quad * 8);
            short8 v1 = *(const short8*)(vbase + (size_t)(16 + l15) * NT + ks * 32 + quad * 8);
            o0 = __builtin_amdgcn_mfma_f32_16x16x32_bf16(v0, pf, o0, 0, 0, 0);
            o1 = __builtin_amdgcn_mfma_f32_16x16x32_bf16(v1, pf, o1, 0, 0, 0);
        }
        // epilogue: normalize, gate, store into per-head plane (full lines)
        short4v g0 = *(const short4v*)(gbase + (size_t)j * CHD + quad * 4);
        short4v g1 = *(const short4v*)(gbase + (size_t)j * CHD + 16 + quad * 4);
        uint2v w0 = {pk_bf2(o0[0] * invs * bf2f(g0[0]), o0[1] * invs * bf2f(g0[1])),
                     pk_bf2(o0[2] * invs * bf2f(g0[2]), o0[3] * invs * bf2f(g0[3]))};
        uint2v w1 = {pk_bf2(o1[0] * invs * bf2f(g1[0]), o1[1] * invs * bf2f(g1[1])),
                     pk_bf2(o1[2] * invs * bf2f(g1[2]), o1[3] * invs * bf2f(g1[3]))};
        size_t ob = ((size_t)h * NT + (size_t)i * 256 + j) * CHD;
        *(uint2v*)&og[ob + quad * 4] = w0;
        *(uint2v*)&og[ob + 16 + quad * 4] = w1;
    }
}

// ---------------------------------------------------------------- kernel 3
// out = og @ Wout.  og is per-head planes [h][row][c]; A-fragment chunk s
// (k = s*32 + quad*8..) maps exactly to plane s at offset quad*8 -> direct
// global loads, no LDS, no barrier.
__global__ __launch_bounds__(256, 4)
void out_gemm(const short* __restrict__ og, const short* __restrict__ woutT,
              float* __restrict__ out) {
    const int tid = threadIdx.x;
    const int wv = tid >> 6, lane = tid & 63;
    const int quad = lane >> 4, l15 = lane & 15;
    const int r0 = blockIdx.x * 64;
    const int row = r0 + wv * 16 + l15;

    short8 af[4];
    #pragma unroll
    for (int s = 0; s < 4; ++s)
        af[s] = *(const short8*)(og + ((size_t)s * NT + row) * CHD + quad * 8);

    f32x4 acc[8];
    #pragma unroll
    for (int ch = 0; ch < 8; ++ch) {
        acc[ch] = f32x4{0.f, 0.f, 0.f, 0.f};
        #pragma unroll
        for (int s = 0; s < 4; ++s) {
            short8 bfrag = *(const short8*)&woutT[(size_t)(ch * 16 + l15) * 128 + s * 32 + quad * 8];
            acc[ch] = __builtin_amdgcn_mfma_f32_16x16x32_bf16(af[s], bfrag, acc[ch], 0, 0, 0);
        }
    }
    #pragma unroll
    for (int ch = 0; ch < 8; ++ch)
        #pragma unroll
        for (int r = 0; r < 4; ++r)
            out[(size_t)(r0 + wv * 16 + quad * 4 + r) * CP + ch * 16 + l15] = acc[ch][r];
}

// ---------------------------------------------------------------- launch
extern "C" void kernel_launch(void* const* d_in, const int* in_sizes, int n_in,
                              void* d_out, int out_size, void* d_ws, size_t ws_size,
                              hipStream_t stream) {
    (void)in_sizes; (void)n_in; (void)out_size; (void)ws_size;
    const float* pair  = (const float*)d_in[0];
    const float* gamma = (const float*)d_in[1];
    const float* beta  = (const float*)d_in[2];
    const float* Wq    = (const float*)d_in[3];
    const float* Wk    = (const float*)d_in[4];
    const float* Wv    = (const float*)d_in[5];
    const float* Wb    = (const float*)d_in[6];
    const float* Wg    = (const float*)d_in[7];
    const float* Wout  = (const float*)d_in[8];
    float* out = (float*)d_out;

    char* ws = (char*)d_ws;
    const size_t SZ_QKVG = (size_t)NH * NT * CHD * 2;           // 16 MB each
    short* wcat  = (short*)(ws);
    short* woutT = (short*)(ws + 135168);
    short* qt    = (short*)(ws + 167936);
    short* kt    = (short*)(ws + 167936 + SZ_QKVG);
    short* vtT   = (short*)(ws + 167936 + 2 * SZ_QKVG);          // [128][NT]
    short* gt    = (short*)(ws + 167936 + 3 * SZ_QKVG);
    float* bt    = (float*)(ws + 167936 + 4 * SZ_QKVG);
    short* og    = (short*)(ws + 167936 + 4 * SZ_QKVG + (size_t)NH * NT * 4);  // [h][row][c]

    hipLaunchKernelGGL(pack_weights, dim3(328), dim3(256), 0, stream,
                       Wq, Wk, Wv, Wb, Wg, Wout, wcat, woutT);
    hipLaunchKernelGGL(ln_proj, dim3(1024), dim3(256), 0, stream,
                       pair, gamma, beta, wcat, qt, kt, vtT, gt, bt);
    hipLaunchKernelGGL(attn, dim3(1024), dim3(256), 0, stream,
                       qt, kt, vtT, gt, bt, og);
    hipLaunchKernelGGL(out_gemm, dim3(1024), dim3(256), 0, stream,
                       og, woutT, out);
}